// Round 10
// baseline (3393.231 us; speedup 1.0000x reference)
//
#include <hip/hip_runtime.h>

typedef __attribute__((ext_vector_type(8))) short bf16x8;
typedef __attribute__((ext_vector_type(4))) float f32x4;

#define C_DIM 256
#define K_CODES 1024
#define HW 1024
#define N_TOK 32768
#define OUT0_ELEMS 8388608
#define MARGIN 2e-3f
#define NSLOT 48
#define TPB 32   // tokens per block in vq_main

static __device__ __forceinline__ unsigned short f2bf(float f) {
    unsigned u = __float_as_uint(f);
    unsigned r = (u + 0x7FFFu + ((u >> 16) & 1u)) >> 16;
    return (unsigned short)r;
}

// ---------------------------------------------------------------------------
// Bk: per-code |w|^2, numpy-pairwise f32 (unchanged from passing kernel).
// ---------------------------------------------------------------------------
__global__ void bk_kernel(const float* __restrict__ cb, float* __restrict__ Bk) {
#pragma clang fp contract(off)
    int k = blockIdx.x * blockDim.x + threadIdx.x;
    if (k >= K_CODES) return;
    const float* w = cb + k * C_DIM;
    float s[2];
    for (int h = 0; h < 2; ++h) {
        const float* p = w + h * 128;
        float r[8];
        #pragma unroll
        for (int j = 0; j < 8; ++j) { float v = p[j]; r[j] = v * v; }
        for (int i = 8; i < 128; i += 8) {
            #pragma unroll
            for (int j = 0; j < 8; ++j) { float v = p[i + j]; r[j] = r[j] + v * v; }
        }
        s[h] = ((r[0] + r[1]) + (r[2] + r[3])) + ((r[4] + r[5]) + (r[6] + r[7]));
    }
    Bk[k] = s[0] + s[1];
}

// ---------------------------------------------------------------------------
// cb -> bf16 copy [K][C]
// ---------------------------------------------------------------------------
__global__ __launch_bounds__(64) void cbh_kernel(const float* __restrict__ cb,
                                                 unsigned short* __restrict__ cb_h) {
    int k = blockIdx.x, l = threadIdx.x;
    const float4 v = *(const float4*)&cb[k * C_DIM + l * 4];
    ushort4 o;
    o.x = f2bf(v.x); o.y = f2bf(v.y); o.z = f2bf(v.z); o.w = f2bf(v.w);
    *(ushort4*)&cb_h[k * C_DIM + l * 4] = o;
}

// ---------------------------------------------------------------------------
// z prep: NCHW f32 -> z_t f32 [N][C] (in d_out region, overwritten later by
// out_kernel), z_h bf16 [N][C], A[N] = |z|^2 numpy-pairwise.
// ---------------------------------------------------------------------------
__global__ __launch_bounds__(256) void zprep_kernel(const float* __restrict__ z,
        float* __restrict__ z_t, unsigned short* __restrict__ z_h,
        float* __restrict__ A) {
#pragma clang fp contract(off)
    __shared__ float tile[64 * 257];
    const int t = threadIdx.x, blk = blockIdx.x;
    const int b = blk >> 4, hw0 = (blk & 15) * 64, tok0 = blk * 64;
    const size_t zb = (size_t)b * (C_DIM * HW) + hw0;
    for (int i = 0; i < 64; ++i) {
        int pos = i * 256 + t;
        int c = pos >> 6, hw = pos & 63;
        tile[hw * 257 + c] = z[zb + (size_t)c * HW + hw];
    }
    __syncthreads();
    if (t < 64) {
        const float* p0 = &tile[t * 257];
        float s[2];
        for (int h = 0; h < 2; ++h) {
            const float* p = p0 + h * 128;
            float r[8];
            #pragma unroll
            for (int j = 0; j < 8; ++j) { float v = p[j]; r[j] = v * v; }
            for (int i = 8; i < 128; i += 8) {
                #pragma unroll
                for (int j = 0; j < 8; ++j) { float v = p[i + j]; r[j] = r[j] + v * v; }
            }
            s[h] = ((r[0] + r[1]) + (r[2] + r[3])) + ((r[4] + r[5]) + (r[6] + r[7]));
        }
        A[tok0 + t] = s[0] + s[1];
    }
    for (int i = 0; i < 64; ++i) {
        int pos = i * 256 + t;
        int tl = pos >> 8, c = pos & 255;
        float v = tile[tl * 257 + c];
        z_t[(size_t)(tok0 + tl) * 256 + c] = v;
        z_h[(size_t)(tok0 + tl) * 256 + c] = f2bf(v);
    }
}

// ---------------------------------------------------------------------------
// Main: per 32-token block (1024 blocks). Single bf16-MFMA sweep. Chunk 0
// establishes a FIXED per-token threshold thr = min(est over 64 codes) +
// MARGIN (>= final_min + MARGIN -> sound superset). Chunks 1..15 are
// barrier-free: {global B loads, ds_read A, MFMA, compare, rare LDS push}.
// No top-k register state. Exact f32 rescore -> idx.
// ---------------------------------------------------------------------------
__global__ __launch_bounds__(256)
__attribute__((amdgpu_waves_per_eu(4, 4)))
void vq_main(
        const unsigned short* __restrict__ z_h, const unsigned short* __restrict__ cb_h,
        const float* __restrict__ A, const float* __restrict__ Bk,
        const float* __restrict__ z_t, const float* __restrict__ cb,
        float* __restrict__ out_idx) {
#pragma clang fp contract(off)
    __shared__ __align__(16) char zs[TPB * 256 * 2];   // 16 KB
    __shared__ float gpart[TPB][4];
    __shared__ int   cnt[TPB];
    __shared__ int   ck[TPB * NSLOT];
    __shared__ float cd[TPB * NSLOT];

    const int tid = threadIdx.x;
    const int w = tid >> 6, l = tid & 63;
    const int lq = l >> 4, lr = l & 15;
    const int tok0 = blockIdx.x * TPB;

    // stage z tile (32 tok x 256 c bf16), layout [c8][tok] 16B units, XOR-swz
    for (int i = 0; i < 4; ++i) {
        int unit = i * 256 + tid;            // 0..1023
        int tok = unit >> 5, c8 = unit & 31;
        uint4 v = *(const uint4*)(z_h + (size_t)(tok0 + tok) * 256 + c8 * 8);
        *(uint4*)(zs + c8 * 512 + ((tok * 16) ^ ((c8 & 7) << 4))) = v;
    }
    if (tid < TPB) cnt[tid] = 0;

    float A_l[8];
    #pragma unroll
    for (int s = 0; s < 8; ++s)
        A_l[s] = A[tok0 + (s >> 2) * 16 + lq * 4 + (s & 3)];

    __syncthreads();

    // ---- chunk 0: compute est, derive fixed per-token threshold ----
    float est0[8];
    {
        const int kcode = w * 16 + lr;
        const float bkvv = Bk[kcode];
        const unsigned short* bp = cb_h + (size_t)kcode * 256 + lq * 8;
        bf16x8 bfr[8];
        #pragma unroll
        for (int cs = 0; cs < 8; ++cs)
            bfr[cs] = *(const bf16x8*)(bp + cs * 32);
        f32x4 acc[2];
        acc[0] = (f32x4){0.f, 0.f, 0.f, 0.f};
        acc[1] = (f32x4){0.f, 0.f, 0.f, 0.f};
        #pragma unroll
        for (int cs = 0; cs < 8; ++cs) {
            const int c8 = cs * 4 + lq;
            const int xorm = (c8 & 7) << 4;
            bf16x8 a0 = *(const bf16x8*)(zs + c8 * 512 + (((lr) * 16) ^ xorm));
            acc[0] = __builtin_amdgcn_mfma_f32_16x16x32_bf16(a0, bfr[cs], acc[0], 0, 0, 0);
            bf16x8 a1 = *(const bf16x8*)(zs + c8 * 512 + (((16 + lr) * 16) ^ xorm));
            acc[1] = __builtin_amdgcn_mfma_f32_16x16x32_bf16(a1, bfr[cs], acc[1], 0, 0, 0);
        }
        #pragma unroll
        for (int s = 0; s < 8; ++s)
            est0[s] = fmaf(-2.0f, acc[s >> 2][s & 3], A_l[s] + bkvv);
        // per-token min over the 16 lr-lanes, cross-wave via gpart
        #pragma unroll
        for (int s = 0; s < 8; ++s) {
            float v = est0[s];
            v = fminf(v, __shfl_xor(v, 1));
            v = fminf(v, __shfl_xor(v, 2));
            v = fminf(v, __shfl_xor(v, 4));
            v = fminf(v, __shfl_xor(v, 8));
            if (lr == 0) gpart[(s >> 2) * 16 + lq * 4 + (s & 3)][w] = v;
        }
    }
    __syncthreads();

    float thr[8];
    #pragma unroll
    for (int s = 0; s < 8; ++s) {
        int tl = (s >> 2) * 16 + lq * 4 + (s & 3);
        thr[s] = fminf(fminf(gpart[tl][0], gpart[tl][1]),
                       fminf(gpart[tl][2], gpart[tl][3])) + MARGIN;
    }
    // collect chunk-0 candidates
    #pragma unroll
    for (int s = 0; s < 8; ++s) {
        if (est0[s] <= thr[s]) {
            int tl = (s >> 2) * 16 + lq * 4 + (s & 3);
            int pos = atomicAdd(&cnt[tl], 1);
            if (pos < NSLOT) ck[tl * NSLOT + pos] = w * 16 + lr;
        }
    }

    // ---- chunks 1..15: barrier-free scan, fixed threshold ----
    for (int kc = 1; kc < 16; ++kc) {
        const int kcode = kc * 64 + w * 16 + lr;
        const float bkvv = Bk[kcode];
        const unsigned short* bp = cb_h + (size_t)kcode * 256 + lq * 8;
        bf16x8 bfr[8];
        #pragma unroll
        for (int cs = 0; cs < 8; ++cs)
            bfr[cs] = *(const bf16x8*)(bp + cs * 32);
        f32x4 acc[2];
        acc[0] = (f32x4){0.f, 0.f, 0.f, 0.f};
        acc[1] = (f32x4){0.f, 0.f, 0.f, 0.f};
        #pragma unroll
        for (int cs = 0; cs < 8; ++cs) {
            const int c8 = cs * 4 + lq;
            const int xorm = (c8 & 7) << 4;
            bf16x8 a0 = *(const bf16x8*)(zs + c8 * 512 + (((lr) * 16) ^ xorm));
            acc[0] = __builtin_amdgcn_mfma_f32_16x16x32_bf16(a0, bfr[cs], acc[0], 0, 0, 0);
            bf16x8 a1 = *(const bf16x8*)(zs + c8 * 512 + (((16 + lr) * 16) ^ xorm));
            acc[1] = __builtin_amdgcn_mfma_f32_16x16x32_bf16(a1, bfr[cs], acc[1], 0, 0, 0);
        }
        #pragma unroll
        for (int s = 0; s < 8; ++s) {
            float est = fmaf(-2.0f, acc[s >> 2][s & 3], A_l[s] + bkvv);
            if (est <= thr[s]) {
                int tl = (s >> 2) * 16 + lq * 4 + (s & 3);
                int pos = atomicAdd(&cnt[tl], 1);
                if (pos < NSLOT) ck[tl * NSLOT + pos] = kcode;
            }
        }
    }
    __syncthreads();

    // exact rescore of candidates (identical arithmetic to the passing kernel)
    {
        int tl = tid >> 3;
        int n = min(cnt[tl], NSLOT);
        const float* zr = z_t + (size_t)(tok0 + tl) * 256;
        float Ag = A[tok0 + tl];
        for (int s = tid & 7; s < n; s += 8) {
            int k = ck[tl * NSLOT + s];
            const float* wr = cb + (size_t)k * 256;
            float acc = 0.0f;
            for (int c = 0; c < 256; c += 4) {
                float4 zv = *(const float4*)&zr[c];
                float4 wv = *(const float4*)&wr[c];
                acc = fmaf(zv.x, wv.x, acc);
                acc = fmaf(zv.y, wv.y, acc);
                acc = fmaf(zv.z, wv.z, acc);
                acc = fmaf(zv.w, wv.w, acc);
            }
            cd[tl * NSLOT + s] = fmaf(-2.0f, acc, Ag + Bk[k]);
        }
    }
    __syncthreads();
    if (tid < TPB) {
        int n = cnt[tid];
        float bd = 3.4e38f; int bki = 0x7fffffff;
        if (n <= NSLOT) {
            for (int s = 0; s < n; ++s) {
                float d = cd[tid * NSLOT + s]; int k = ck[tid * NSLOT + s];
                if (d < bd || (d == bd && k < bki)) { bd = d; bki = k; }
            }
        } else {
            // sound fallback (P ~ 1e-12): exact scan of all codes
            const float* zr = z_t + (size_t)(tok0 + tid) * 256;
            float Ag = A[tok0 + tid];
            for (int k = 0; k < K_CODES; ++k) {
                const float* wr = cb + (size_t)k * 256;
                float acc = 0.0f;
                for (int c = 0; c < 256; c += 4) {
                    float4 zv = *(const float4*)&zr[c];
                    float4 wv = *(const float4*)&wr[c];
                    acc = fmaf(zv.x, wv.x, acc);
                    acc = fmaf(zv.y, wv.y, acc);
                    acc = fmaf(zv.z, wv.z, acc);
                    acc = fmaf(zv.w, wv.w, acc);
                }
                float d = fmaf(-2.0f, acc, Ag + Bk[k]);
                if (d < bd) { bd = d; bki = k; }
            }
        }
        out_idx[tok0 + tid] = (float)bki;
    }
}

// ---------------------------------------------------------------------------
// Output: out0 = z + (w - z) elementwise (NCHW), loss partials.
// ---------------------------------------------------------------------------
__global__ __launch_bounds__(256, 2) void out_kernel(const float* __restrict__ z,
        const float* __restrict__ cb, const float* __restrict__ out_idx_f,
        float* __restrict__ out0, double* __restrict__ lacc) {
#pragma clang fp contract(off)
    __shared__ float wl[64 * 257];
    __shared__ int fi[64];
    __shared__ double red[256];
    const int t = threadIdx.x, blk = blockIdx.x;
    const int b = blk >> 4, hw0 = (blk & 15) * 64;
    const size_t zb = (size_t)b * (C_DIM * HW) + hw0;
    if (t < 64) fi[t] = (int)out_idx_f[blk * 64 + t];
    __syncthreads();
    for (int i = 0; i < 64; ++i) {
        int pos = i * 256 + t;
        int row = pos >> 8, c = pos & 255;
        wl[row * 257 + c] = cb[(size_t)fi[row] * 256 + c];
    }
    __syncthreads();
    double lsum = 0.0;
    for (int i = 0; i < 64; ++i) {
        int pos = i * 256 + t;
        int c = pos >> 6, hw = pos & 63;
        float zv = z[zb + (size_t)c * HW + hw];
        float wv = wl[hw * 257 + c];
        float d = wv - zv;
        out0[zb + (size_t)c * HW + hw] = zv + d;
        float q = d * d;
        lsum += (double)q;
    }
    red[t] = lsum;
    __syncthreads();
    if (t == 0) {
        double s = 0.0;
        for (int i = 0; i < 256; ++i) s += red[i];
        atomicAdd(lacc, s);
    }
}

__global__ void loss_kernel(const double* __restrict__ acc, float* __restrict__ out_loss) {
    double mse = acc[0] / (double)OUT0_ELEMS;
    out_loss[0] = (float)(mse + 0.25 * mse);
}

extern "C" void kernel_launch(void* const* d_in, const int* in_sizes, int n_in,
                              void* d_out, int out_size, void* d_ws, size_t ws_size,
                              hipStream_t stream) {
    const float* z  = (const float*)d_in[0];
    const float* cb = (const float*)d_in[1];
    float* out      = (float*)d_out;
    float* out_idx  = out + OUT0_ELEMS;
    float* out_loss = out + OUT0_ELEMS + N_TOK;

    char* wsb = (char*)d_ws;
    double*         lacc = (double*)wsb;                       // 64 B
    float*          Bk   = (float*)(wsb + 64);                 // 4 KB
    float*          A    = (float*)(wsb + 8192);               // 128 KB
    unsigned short* cb_h = (unsigned short*)(wsb + 262144);    // 512 KB
    unsigned short* z_h  = (unsigned short*)(wsb + 1048576);   // 16 MB
    float*          z_t  = out;  // reuse out0 region as [N][C] f32 scratch

    hipMemsetAsync(d_ws, 0, 64, stream);
    zprep_kernel<<<512, 256, 0, stream>>>(z, z_t, z_h, A);
    bk_kernel<<<4, 256, 0, stream>>>(cb, Bk);
    cbh_kernel<<<1024, 64, 0, stream>>>(cb, cb_h);
    vq_main<<<1024, 256, 0, stream>>>(z_h, cb_h, A, Bk, z_t, cb, out_idx);
    out_kernel<<<512, 256, 0, stream>>>(z, cb, out_idx, out, lacc);
    loss_kernel<<<1, 1, 0, stream>>>(lacc, out_loss);
}

// Round 11
// 2138.779 us; speedup vs baseline: 1.5865x; 1.5865x over previous
//
#include <hip/hip_runtime.h>

typedef __attribute__((ext_vector_type(8))) short bf16x8;
typedef __attribute__((ext_vector_type(4))) float f32x4;

#define C_DIM 256
#define K_CODES 1024
#define HW 1024
#define N_TOK 32768
#define OUT0_ELEMS 8388608
#define MARGIN 2e-3f
#define NSLOT 32

static __device__ __forceinline__ unsigned short f2bf(float f) {
    unsigned u = __float_as_uint(f);
    unsigned r = (u + 0x7FFFu + ((u >> 16) & 1u)) >> 16;
    return (unsigned short)r;
}

// ---------------------------------------------------------------------------
// Bk: per-code |w|^2, numpy-pairwise f32 (unchanged from passing kernel).
// ---------------------------------------------------------------------------
__global__ void bk_kernel(const float* __restrict__ cb, float* __restrict__ Bk) {
#pragma clang fp contract(off)
    int k = blockIdx.x * blockDim.x + threadIdx.x;
    if (k >= K_CODES) return;
    const float* w = cb + k * C_DIM;
    float s[2];
    for (int h = 0; h < 2; ++h) {
        const float* p = w + h * 128;
        float r[8];
        #pragma unroll
        for (int j = 0; j < 8; ++j) { float v = p[j]; r[j] = v * v; }
        for (int i = 8; i < 128; i += 8) {
            #pragma unroll
            for (int j = 0; j < 8; ++j) { float v = p[i + j]; r[j] = r[j] + v * v; }
        }
        s[h] = ((r[0] + r[1]) + (r[2] + r[3])) + ((r[4] + r[5]) + (r[6] + r[7]));
    }
    Bk[k] = s[0] + s[1];
}

// ---------------------------------------------------------------------------
// cb -> bf16 copy [K][C]
// ---------------------------------------------------------------------------
__global__ __launch_bounds__(64) void cbh_kernel(const float* __restrict__ cb,
                                                 unsigned short* __restrict__ cb_h) {
    int k = blockIdx.x, l = threadIdx.x;
    const float4 v = *(const float4*)&cb[k * C_DIM + l * 4];
    ushort4 o;
    o.x = f2bf(v.x); o.y = f2bf(v.y); o.z = f2bf(v.z); o.w = f2bf(v.w);
    *(ushort4*)&cb_h[k * C_DIM + l * 4] = o;
}

// ---------------------------------------------------------------------------
// z prep: NCHW f32 -> z_t f32 [N][C] (in d_out region, overwritten later by
// out_kernel), z_h bf16 [N][C], A[N] = |z|^2 numpy-pairwise.
// ---------------------------------------------------------------------------
__global__ __launch_bounds__(256) void zprep_kernel(const float* __restrict__ z,
        float* __restrict__ z_t, unsigned short* __restrict__ z_h,
        float* __restrict__ A) {
#pragma clang fp contract(off)
    __shared__ float tile[64 * 257];
    const int t = threadIdx.x, blk = blockIdx.x;
    const int b = blk >> 4, hw0 = (blk & 15) * 64, tok0 = blk * 64;
    const size_t zb = (size_t)b * (C_DIM * HW) + hw0;
    for (int i = 0; i < 64; ++i) {
        int pos = i * 256 + t;
        int c = pos >> 6, hw = pos & 63;
        tile[hw * 257 + c] = z[zb + (size_t)c * HW + hw];
    }
    __syncthreads();
    if (t < 64) {
        const float* p0 = &tile[t * 257];
        float s[2];
        for (int h = 0; h < 2; ++h) {
            const float* p = p0 + h * 128;
            float r[8];
            #pragma unroll
            for (int j = 0; j < 8; ++j) { float v = p[j]; r[j] = v * v; }
            for (int i = 8; i < 128; i += 8) {
                #pragma unroll
                for (int j = 0; j < 8; ++j) { float v = p[i + j]; r[j] = r[j] + v * v; }
            }
            s[h] = ((r[0] + r[1]) + (r[2] + r[3])) + ((r[4] + r[5]) + (r[6] + r[7]));
        }
        A[tok0 + t] = s[0] + s[1];
    }
    for (int i = 0; i < 64; ++i) {
        int pos = i * 256 + t;
        int tl = pos >> 8, c = pos & 255;
        float v = tile[tl * 257 + c];
        z_t[(size_t)(tok0 + tl) * 256 + c] = v;
        z_h[(size_t)(tok0 + tl) * 256 + c] = f2bf(v);
    }
}

// ---------------------------------------------------------------------------
// Main: per 64-token block (512 blocks) — the Round-6 proven structure with
// the second sweep removed. Single sweep; threshold established from chunk 0
// (min over 64 codes + MARGIN) and refined after chunk 3 (min over 256 codes
// + MARGIN). Both thresholds >= global_min_est + MARGIN -> collection is a
// sound superset of {exact argmin and ties}. Exact f32 rescore -> idx.
// ---------------------------------------------------------------------------
__global__ __launch_bounds__(256, 2) void vq_main(
        const unsigned short* __restrict__ z_h, const unsigned short* __restrict__ cb_h,
        const float* __restrict__ A, const float* __restrict__ Bk,
        const float* __restrict__ z_t, const float* __restrict__ cb,
        float* __restrict__ out_idx) {
#pragma clang fp contract(off)
    __shared__ __align__(16) char zs[32768];
    __shared__ __align__(16) char wsm[32768];
    __shared__ float gpart[64][4];
    __shared__ int   cnt[64];
    __shared__ unsigned short ck[64 * NSLOT];
    __shared__ float cd[64 * NSLOT];

    const int tid = threadIdx.x;
    const int w = tid >> 6, l = tid & 63;
    const int lq = l >> 4, lr = l & 15;
    const int tok0 = blockIdx.x * 64;

    // stage z tile (64 tok x 256 c bf16), layout [c8][tok] 16B units, XOR-swz
    for (int i = 0; i < 8; ++i) {
        int unit = i * 256 + tid;
        int tok = unit >> 5, c8 = unit & 31;
        uint4 v = *(const uint4*)(z_h + (size_t)(tok0 + tok) * 256 + c8 * 8);
        *(uint4*)(zs + c8 * 1024 + ((tok * 16) ^ ((c8 & 7) << 4))) = v;
    }
    if (tid < 64) cnt[tid] = 0;
    __syncthreads();

    // hoist A-fragments: afr[rt][cs]; lane holds z[rt*16+lr][cs*32+lq*8 ..+8]
    bf16x8 afr[4][8];
    #pragma unroll
    for (int rt = 0; rt < 4; ++rt)
        #pragma unroll
        for (int cs = 0; cs < 8; ++cs) {
            int tok = rt * 16 + lr;
            int c8 = cs * 4 + lq;
            afr[rt][cs] = *(const bf16x8*)(zs + c8 * 1024 + ((tok * 16) ^ ((c8 & 7) << 4)));
        }

    float A_l[16];
    #pragma unroll
    for (int s = 0; s < 16; ++s)
        A_l[s] = A[tok0 + (s >> 2) * 16 + lq * 4 + (s & 3)];

    float rmin[16], thr[16];
    #pragma unroll
    for (int s = 0; s < 16; ++s) { rmin[s] = 3.4e38f; thr[s] = 3.4e38f; }

    for (int kc = 0; kc < 16; ++kc) {
        __syncthreads();
        // stage 64-code chunk of bf16 codebook, same layout/swizzle
        for (int i = 0; i < 8; ++i) {
            int unit = i * 256 + tid;
            int code = unit >> 5, c8 = unit & 31;
            uint4 v = *(const uint4*)(cb_h + (size_t)(kc * 64 + code) * 256 + c8 * 8);
            *(uint4*)(wsm + c8 * 1024 + ((code * 16) ^ ((c8 & 7) << 4))) = v;
        }
        __syncthreads();
        const int kcode = kc * 64 + w * 16 + lr;   // this lane's code column
        const float bkv = Bk[kcode];
        f32x4 acc[4];
        #pragma unroll
        for (int rt = 0; rt < 4; ++rt) acc[rt] = (f32x4){0.f, 0.f, 0.f, 0.f};
        #pragma unroll
        for (int cs = 0; cs < 8; ++cs) {
            int c8 = cs * 4 + lq;
            int codeb = w * 16 + lr;
            bf16x8 bfr = *(const bf16x8*)(wsm + c8 * 1024 + ((codeb * 16) ^ ((c8 & 7) << 4)));
            #pragma unroll
            for (int rt = 0; rt < 4; ++rt)
                acc[rt] = __builtin_amdgcn_mfma_f32_16x16x32_bf16(afr[rt][cs], bfr, acc[rt], 0, 0, 0);
        }

        float est[16];
        #pragma unroll
        for (int s = 0; s < 16; ++s) {
            est[s] = fmaf(-2.0f, acc[s >> 2][s & 3], A_l[s] + bkv);
            rmin[s] = fminf(rmin[s], est[s]);
        }

        // threshold establish (kc==0) / refine (kc==3): reduce rmin -> thr
        if (kc == 0 || kc == 3) {
            #pragma unroll
            for (int s = 0; s < 16; ++s) {
                float v = rmin[s];
                v = fminf(v, __shfl_xor(v, 1));
                v = fminf(v, __shfl_xor(v, 2));
                v = fminf(v, __shfl_xor(v, 4));
                v = fminf(v, __shfl_xor(v, 8));
                if (lr == 0) gpart[(s >> 2) * 16 + lq * 4 + (s & 3)][w] = v;
            }
            __syncthreads();
            #pragma unroll
            for (int s = 0; s < 16; ++s) {
                int tl = (s >> 2) * 16 + lq * 4 + (s & 3);
                thr[s] = fminf(fminf(gpart[tl][0], gpart[tl][1]),
                               fminf(gpart[tl][2], gpart[tl][3])) + MARGIN;
            }
        }

        // collect candidates under the current (sound, monotone) threshold
        #pragma unroll
        for (int s = 0; s < 16; ++s) {
            if (est[s] <= thr[s]) {
                int tl = (s >> 2) * 16 + lq * 4 + (s & 3);
                int pos = atomicAdd(&cnt[tl], 1);
                if (pos < NSLOT) ck[tl * NSLOT + pos] = (unsigned short)kcode;
            }
        }
    }
    __syncthreads();

    // exact rescore of candidates (identical arithmetic to the passing kernel)
    {
        int tl = tid >> 2;
        int n = min(cnt[tl], NSLOT);
        const float* zr = z_t + (size_t)(tok0 + tl) * 256;
        float Ag = A[tok0 + tl];
        for (int s = tid & 3; s < n; s += 4) {
            int k = ck[tl * NSLOT + s];
            const float* wr = cb + (size_t)k * 256;
            float acc = 0.0f;
            for (int c = 0; c < 256; c += 4) {
                float4 zv = *(const float4*)&zr[c];
                float4 wv = *(const float4*)&wr[c];
                acc = fmaf(zv.x, wv.x, acc);
                acc = fmaf(zv.y, wv.y, acc);
                acc = fmaf(zv.z, wv.z, acc);
                acc = fmaf(zv.w, wv.w, acc);
            }
            cd[tl * NSLOT + s] = fmaf(-2.0f, acc, Ag + Bk[k]);
        }
    }
    __syncthreads();
    if (tid < 64) {
        int n = cnt[tid];
        float bd = 3.4e38f; int bki = 0x7fffffff;
        if (n <= NSLOT) {
            for (int s = 0; s < n; ++s) {
                float d = cd[tid * NSLOT + s]; int k = ck[tid * NSLOT + s];
                if (d < bd || (d == bd && k < bki)) { bd = d; bki = k; }
            }
        } else {
            // sound fallback (P ~ 1e-8 grid-wide): exact scan of all codes
            const float* zr = z_t + (size_t)(tok0 + tid) * 256;
            float Ag = A[tok0 + tid];
            for (int k = 0; k < K_CODES; ++k) {
                const float* wr = cb + (size_t)k * 256;
                float acc = 0.0f;
                for (int c = 0; c < 256; c += 4) {
                    float4 zv = *(const float4*)&zr[c];
                    float4 wv = *(const float4*)&wr[c];
                    acc = fmaf(zv.x, wv.x, acc);
                    acc = fmaf(zv.y, wv.y, acc);
                    acc = fmaf(zv.z, wv.z, acc);
                    acc = fmaf(zv.w, wv.w, acc);
                }
                float d = fmaf(-2.0f, acc, Ag + Bk[k]);
                if (d < bd) { bd = d; bki = k; }
            }
        }
        out_idx[tok0 + tid] = (float)bki;
    }
}

// ---------------------------------------------------------------------------
// Output: out0 = z + (w - z) elementwise (NCHW), loss partials.
// ---------------------------------------------------------------------------
__global__ __launch_bounds__(256, 2) void out_kernel(const float* __restrict__ z,
        const float* __restrict__ cb, const float* __restrict__ out_idx_f,
        float* __restrict__ out0, double* __restrict__ lacc) {
#pragma clang fp contract(off)
    __shared__ float wl[64 * 257];
    __shared__ int fi[64];
    __shared__ double red[256];
    const int t = threadIdx.x, blk = blockIdx.x;
    const int b = blk >> 4, hw0 = (blk & 15) * 64;
    const size_t zb = (size_t)b * (C_DIM * HW) + hw0;
    if (t < 64) fi[t] = (int)out_idx_f[blk * 64 + t];
    __syncthreads();
    for (int i = 0; i < 64; ++i) {
        int pos = i * 256 + t;
        int row = pos >> 8, c = pos & 255;
        wl[row * 257 + c] = cb[(size_t)fi[row] * 256 + c];
    }
    __syncthreads();
    double lsum = 0.0;
    for (int i = 0; i < 64; ++i) {
        int pos = i * 256 + t;
        int c = pos >> 6, hw = pos & 63;
        float zv = z[zb + (size_t)c * HW + hw];
        float wv = wl[hw * 257 + c];
        float d = wv - zv;
        out0[zb + (size_t)c * HW + hw] = zv + d;
        float q = d * d;
        lsum += (double)q;
    }
    red[t] = lsum;
    __syncthreads();
    if (t == 0) {
        double s = 0.0;
        for (int i = 0; i < 256; ++i) s += red[i];
        atomicAdd(lacc, s);
    }
}

__global__ void loss_kernel(const double* __restrict__ acc, float* __restrict__ out_loss) {
    double mse = acc[0] / (double)OUT0_ELEMS;
    out_loss[0] = (float)(mse + 0.25 * mse);
}

extern "C" void kernel_launch(void* const* d_in, const int* in_sizes, int n_in,
                              void* d_out, int out_size, void* d_ws, size_t ws_size,
                              hipStream_t stream) {
    const float* z  = (const float*)d_in[0];
    const float* cb = (const float*)d_in[1];
    float* out      = (float*)d_out;
    float* out_idx  = out + OUT0_ELEMS;
    float* out_loss = out + OUT0_ELEMS + N_TOK;

    char* wsb = (char*)d_ws;
    double*         lacc = (double*)wsb;                       // 64 B
    float*          Bk   = (float*)(wsb + 64);                 // 4 KB
    float*          A    = (float*)(wsb + 8192);               // 128 KB
    unsigned short* cb_h = (unsigned short*)(wsb + 262144);    // 512 KB
    unsigned short* z_h  = (unsigned short*)(wsb + 1048576);   // 16 MB
    float*          z_t  = out;  // reuse out0 region as [N][C] f32 scratch

    hipMemsetAsync(d_ws, 0, 64, stream);
    zprep_kernel<<<512, 256, 0, stream>>>(z, z_t, z_h, A);
    bk_kernel<<<4, 256, 0, stream>>>(cb, Bk);
    cbh_kernel<<<1024, 64, 0, stream>>>(cb, cb_h);
    vq_main<<<512, 256, 0, stream>>>(z_h, cb_h, A, Bk, z_t, cb, out_idx);
    out_kernel<<<512, 256, 0, stream>>>(z, cb, out_idx, out, lacc);
    loss_kernel<<<1, 1, 0, stream>>>(lacc, out_loss);
}

// Round 12
// 1993.754 us; speedup vs baseline: 1.7019x; 1.0727x over previous
//
#include <hip/hip_runtime.h>

typedef __attribute__((ext_vector_type(8))) short bf16x8;
typedef __attribute__((ext_vector_type(4))) float f32x4;

#define C_DIM 256
#define K_CODES 1024
#define HW 1024
#define N_TOK 32768
#define OUT0_ELEMS 8388608
#define MARGIN 2e-3f
#define NSLOT 32

static __device__ __forceinline__ unsigned short f2bf(float f) {
    unsigned u = __float_as_uint(f);
    unsigned r = (u + 0x7FFFu + ((u >> 16) & 1u)) >> 16;
    return (unsigned short)r;
}

// ---------------------------------------------------------------------------
// Bk: per-code |w|^2, numpy-pairwise f32 (unchanged from passing kernel).
// ---------------------------------------------------------------------------
__global__ void bk_kernel(const float* __restrict__ cb, float* __restrict__ Bk) {
#pragma clang fp contract(off)
    int k = blockIdx.x * blockDim.x + threadIdx.x;
    if (k >= K_CODES) return;
    const float* w = cb + k * C_DIM;
    float s[2];
    for (int h = 0; h < 2; ++h) {
        const float* p = w + h * 128;
        float r[8];
        #pragma unroll
        for (int j = 0; j < 8; ++j) { float v = p[j]; r[j] = v * v; }
        for (int i = 8; i < 128; i += 8) {
            #pragma unroll
            for (int j = 0; j < 8; ++j) { float v = p[i + j]; r[j] = r[j] + v * v; }
        }
        s[h] = ((r[0] + r[1]) + (r[2] + r[3])) + ((r[4] + r[5]) + (r[6] + r[7]));
    }
    Bk[k] = s[0] + s[1];
}

// ---------------------------------------------------------------------------
// cb -> bf16 copy [K][C]
// ---------------------------------------------------------------------------
__global__ __launch_bounds__(64) void cbh_kernel(const float* __restrict__ cb,
                                                 unsigned short* __restrict__ cb_h) {
    int k = blockIdx.x, l = threadIdx.x;
    const float4 v = *(const float4*)&cb[k * C_DIM + l * 4];
    ushort4 o;
    o.x = f2bf(v.x); o.y = f2bf(v.y); o.z = f2bf(v.z); o.w = f2bf(v.w);
    *(ushort4*)&cb_h[k * C_DIM + l * 4] = o;
}

// ---------------------------------------------------------------------------
// z prep: NCHW f32 -> z_t f32 [N][C] (in d_out region, overwritten later by
// out_kernel), z_h bf16 [N][C], A[N] = |z|^2 numpy-pairwise.
// ---------------------------------------------------------------------------
__global__ __launch_bounds__(256) void zprep_kernel(const float* __restrict__ z,
        float* __restrict__ z_t, unsigned short* __restrict__ z_h,
        float* __restrict__ A) {
#pragma clang fp contract(off)
    __shared__ float tile[64 * 257];
    const int t = threadIdx.x, blk = blockIdx.x;
    const int b = blk >> 4, hw0 = (blk & 15) * 64, tok0 = blk * 64;
    const size_t zb = (size_t)b * (C_DIM * HW) + hw0;
    for (int i = 0; i < 64; ++i) {
        int pos = i * 256 + t;
        int c = pos >> 6, hw = pos & 63;
        tile[hw * 257 + c] = z[zb + (size_t)c * HW + hw];
    }
    __syncthreads();
    if (t < 64) {
        const float* p0 = &tile[t * 257];
        float s[2];
        for (int h = 0; h < 2; ++h) {
            const float* p = p0 + h * 128;
            float r[8];
            #pragma unroll
            for (int j = 0; j < 8; ++j) { float v = p[j]; r[j] = v * v; }
            for (int i = 8; i < 128; i += 8) {
                #pragma unroll
                for (int j = 0; j < 8; ++j) { float v = p[i + j]; r[j] = r[j] + v * v; }
            }
            s[h] = ((r[0] + r[1]) + (r[2] + r[3])) + ((r[4] + r[5]) + (r[6] + r[7]));
        }
        A[tok0 + t] = s[0] + s[1];
    }
    for (int i = 0; i < 64; ++i) {
        int pos = i * 256 + t;
        int tl = pos >> 8, c = pos & 255;
        float v = tile[tl * 257 + c];
        z_t[(size_t)(tok0 + tl) * 256 + c] = v;
        z_h[(size_t)(tok0 + tl) * 256 + c] = f2bf(v);
    }
}

// ---------------------------------------------------------------------------
// Main: per 64-token block (512 blocks), R6's proven codegen pattern.
// Filter works in the (Bk - 2*dot) domain: |z|^2 cancels from argmin and
// margin band, so no A in the filter at all.
// Phase A (chunks 0-3): track rminp[16] only (est consumed immediately).
// Reduce -> fixed sound threshold thr = min-over-256 + MARGIN.
// Phase B (chunks 0-15): state = thr[16]+acc; compare+push immediately.
// Exact f32 rescore (bit-identical to passing kernel) -> idx.
// ---------------------------------------------------------------------------
__global__ __launch_bounds__(256, 2) void vq_main(
        const unsigned short* __restrict__ z_h, const unsigned short* __restrict__ cb_h,
        const float* __restrict__ A, const float* __restrict__ Bk,
        const float* __restrict__ z_t, const float* __restrict__ cb,
        float* __restrict__ out_idx) {
#pragma clang fp contract(off)
    __shared__ __align__(16) char zs[32768];
    __shared__ __align__(16) char wsm[32768];
    __shared__ float gpart[64][4];
    __shared__ int   cnt[64];
    __shared__ unsigned short ck[64 * NSLOT];
    __shared__ float cd[64 * NSLOT];

    const int tid = threadIdx.x;
    const int w = tid >> 6, l = tid & 63;
    const int lq = l >> 4, lr = l & 15;
    const int tok0 = blockIdx.x * 64;

    // stage z tile (64 tok x 256 c bf16), layout [c8][tok] 16B units, XOR-swz
    for (int i = 0; i < 8; ++i) {
        int unit = i * 256 + tid;
        int tok = unit >> 5, c8 = unit & 31;
        uint4 v = *(const uint4*)(z_h + (size_t)(tok0 + tok) * 256 + c8 * 8);
        *(uint4*)(zs + c8 * 1024 + ((tok * 16) ^ ((c8 & 7) << 4))) = v;
    }
    if (tid < 64) cnt[tid] = 0;
    __syncthreads();

    // ---- Phase A: chunks 0..3, running min of (Bk - 2*dot) only ----
    float rminp[16];
    #pragma unroll
    for (int s = 0; s < 16; ++s) rminp[s] = 3.4e38f;

    for (int kc = 0; kc < 4; ++kc) {
        __syncthreads();
        for (int i = 0; i < 8; ++i) {
            int unit = i * 256 + tid;
            int code = unit >> 5, c8 = unit & 31;
            uint4 v = *(const uint4*)(cb_h + (size_t)(kc * 64 + code) * 256 + c8 * 8);
            *(uint4*)(wsm + c8 * 1024 + ((code * 16) ^ ((c8 & 7) << 4))) = v;
        }
        __syncthreads();
        const int kcode = kc * 64 + w * 16 + lr;
        const float bkv = Bk[kcode];
        f32x4 acc[4];
        #pragma unroll
        for (int rt = 0; rt < 4; ++rt) acc[rt] = (f32x4){0.f, 0.f, 0.f, 0.f};
        #pragma unroll
        for (int cs = 0; cs < 8; ++cs) {
            int c8 = cs * 4 + lq;
            int codeb = w * 16 + lr;
            bf16x8 bfr = *(const bf16x8*)(wsm + c8 * 1024 + ((codeb * 16) ^ ((c8 & 7) << 4)));
            #pragma unroll
            for (int rt = 0; rt < 4; ++rt) {
                bf16x8 afr = *(const bf16x8*)(zs + c8 * 1024 + (((rt * 16 + lr) * 16) ^ ((c8 & 7) << 4)));
                acc[rt] = __builtin_amdgcn_mfma_f32_16x16x32_bf16(afr, bfr, acc[rt], 0, 0, 0);
            }
        }
        #pragma unroll
        for (int s = 0; s < 16; ++s)
            rminp[s] = fminf(rminp[s], fmaf(-2.0f, acc[s >> 2][s & 3], bkv));
    }

    // ---- one reduce: min over 256 codes -> fixed threshold ----
    #pragma unroll
    for (int s = 0; s < 16; ++s) {
        float v = rminp[s];
        v = fminf(v, __shfl_xor(v, 1));
        v = fminf(v, __shfl_xor(v, 2));
        v = fminf(v, __shfl_xor(v, 4));
        v = fminf(v, __shfl_xor(v, 8));
        if (lr == 0) gpart[(s >> 2) * 16 + lq * 4 + (s & 3)][w] = v;
    }
    __syncthreads();

    float thr[16];
    #pragma unroll
    for (int s = 0; s < 16; ++s) {
        int tl = (s >> 2) * 16 + lq * 4 + (s & 3);
        thr[s] = fminf(fminf(gpart[tl][0], gpart[tl][1]),
                       fminf(gpart[tl][2], gpart[tl][3])) + MARGIN;
    }

    // ---- Phase B: all 16 chunks, collect under fixed sound threshold ----
    for (int kc = 0; kc < 16; ++kc) {
        __syncthreads();
        for (int i = 0; i < 8; ++i) {
            int unit = i * 256 + tid;
            int code = unit >> 5, c8 = unit & 31;
            uint4 v = *(const uint4*)(cb_h + (size_t)(kc * 64 + code) * 256 + c8 * 8);
            *(uint4*)(wsm + c8 * 1024 + ((code * 16) ^ ((c8 & 7) << 4))) = v;
        }
        __syncthreads();
        const int kcode = kc * 64 + w * 16 + lr;
        const float bkv = Bk[kcode];
        f32x4 acc[4];
        #pragma unroll
        for (int rt = 0; rt < 4; ++rt) acc[rt] = (f32x4){0.f, 0.f, 0.f, 0.f};
        #pragma unroll
        for (int cs = 0; cs < 8; ++cs) {
            int c8 = cs * 4 + lq;
            int codeb = w * 16 + lr;
            bf16x8 bfr = *(const bf16x8*)(wsm + c8 * 1024 + ((codeb * 16) ^ ((c8 & 7) << 4)));
            #pragma unroll
            for (int rt = 0; rt < 4; ++rt) {
                bf16x8 afr = *(const bf16x8*)(zs + c8 * 1024 + (((rt * 16 + lr) * 16) ^ ((c8 & 7) << 4)));
                acc[rt] = __builtin_amdgcn_mfma_f32_16x16x32_bf16(afr, bfr, acc[rt], 0, 0, 0);
            }
        }
        #pragma unroll
        for (int s = 0; s < 16; ++s) {
            float est = fmaf(-2.0f, acc[s >> 2][s & 3], bkv);
            if (est <= thr[s]) {
                int tl = (s >> 2) * 16 + lq * 4 + (s & 3);
                int pos = atomicAdd(&cnt[tl], 1);
                if (pos < NSLOT) ck[tl * NSLOT + pos] = (unsigned short)kcode;
            }
        }
    }
    __syncthreads();

    // exact rescore of candidates (identical arithmetic to the passing kernel)
    {
        int tl = tid >> 2;
        int n = min(cnt[tl], NSLOT);
        const float* zr = z_t + (size_t)(tok0 + tl) * 256;
        float Ag = A[tok0 + tl];
        for (int s = tid & 3; s < n; s += 4) {
            int k = ck[tl * NSLOT + s];
            const float* wr = cb + (size_t)k * 256;
            float acc = 0.0f;
            for (int c = 0; c < 256; c += 4) {
                float4 zv = *(const float4*)&zr[c];
                float4 wv = *(const float4*)&wr[c];
                acc = fmaf(zv.x, wv.x, acc);
                acc = fmaf(zv.y, wv.y, acc);
                acc = fmaf(zv.z, wv.z, acc);
                acc = fmaf(zv.w, wv.w, acc);
            }
            cd[tl * NSLOT + s] = fmaf(-2.0f, acc, Ag + Bk[k]);
        }
    }
    __syncthreads();
    if (tid < 64) {
        int n = cnt[tid];
        float bd = 3.4e38f; int bki = 0x7fffffff;
        if (n <= NSLOT) {
            for (int s = 0; s < n; ++s) {
                float d = cd[tid * NSLOT + s]; int k = ck[tid * NSLOT + s];
                if (d < bd || (d == bd && k < bki)) { bd = d; bki = k; }
            }
        } else {
            // sound fallback (P ~ 1e-12 grid-wide): exact scan of all codes
            const float* zr = z_t + (size_t)(tok0 + tid) * 256;
            float Ag = A[tok0 + tid];
            for (int k = 0; k < K_CODES; ++k) {
                const float* wr = cb + (size_t)k * 256;
                float acc = 0.0f;
                for (int c = 0; c < 256; c += 4) {
                    float4 zv = *(const float4*)&zr[c];
                    float4 wv = *(const float4*)&wr[c];
                    acc = fmaf(zv.x, wv.x, acc);
                    acc = fmaf(zv.y, wv.y, acc);
                    acc = fmaf(zv.z, wv.z, acc);
                    acc = fmaf(zv.w, wv.w, acc);
                }
                float d = fmaf(-2.0f, acc, Ag + Bk[k]);
                if (d < bd) { bd = d; bki = k; }
            }
        }
        out_idx[tok0 + tid] = (float)bki;
    }
}

// ---------------------------------------------------------------------------
// Output: out0 = z + (w - z) elementwise (NCHW), loss partials.
// ---------------------------------------------------------------------------
__global__ __launch_bounds__(256, 2) void out_kernel(const float* __restrict__ z,
        const float* __restrict__ cb, const float* __restrict__ out_idx_f,
        float* __restrict__ out0, double* __restrict__ lacc) {
#pragma clang fp contract(off)
    __shared__ float wl[64 * 257];
    __shared__ int fi[64];
    __shared__ double red[256];
    const int t = threadIdx.x, blk = blockIdx.x;
    const int b = blk >> 4, hw0 = (blk & 15) * 64;
    const size_t zb = (size_t)b * (C_DIM * HW) + hw0;
    if (t < 64) fi[t] = (int)out_idx_f[blk * 64 + t];
    __syncthreads();
    for (int i = 0; i < 64; ++i) {
        int pos = i * 256 + t;
        int row = pos >> 8, c = pos & 255;
        wl[row * 257 + c] = cb[(size_t)fi[row] * 256 + c];
    }
    __syncthreads();
    double lsum = 0.0;
    for (int i = 0; i < 64; ++i) {
        int pos = i * 256 + t;
        int c = pos >> 6, hw = pos & 63;
        float zv = z[zb + (size_t)c * HW + hw];
        float wv = wl[hw * 257 + c];
        float d = wv - zv;
        out0[zb + (size_t)c * HW + hw] = zv + d;
        float q = d * d;
        lsum += (double)q;
    }
    red[t] = lsum;
    __syncthreads();
    if (t == 0) {
        double s = 0.0;
        for (int i = 0; i < 256; ++i) s += red[i];
        atomicAdd(lacc, s);
    }
}

__global__ void loss_kernel(const double* __restrict__ acc, float* __restrict__ out_loss) {
    double mse = acc[0] / (double)OUT0_ELEMS;
    out_loss[0] = (float)(mse + 0.25 * mse);
}

extern "C" void kernel_launch(void* const* d_in, const int* in_sizes, int n_in,
                              void* d_out, int out_size, void* d_ws, size_t ws_size,
                              hipStream_t stream) {
    const float* z  = (const float*)d_in[0];
    const float* cb = (const float*)d_in[1];
    float* out      = (float*)d_out;
    float* out_idx  = out + OUT0_ELEMS;
    float* out_loss = out + OUT0_ELEMS + N_TOK;

    char* wsb = (char*)d_ws;
    double*         lacc = (double*)wsb;                       // 64 B
    float*          Bk   = (float*)(wsb + 64);                 // 4 KB
    float*          A    = (float*)(wsb + 8192);               // 128 KB
    unsigned short* cb_h = (unsigned short*)(wsb + 262144);    // 512 KB
    unsigned short* z_h  = (unsigned short*)(wsb + 1048576);   // 16 MB
    float*          z_t  = out;  // reuse out0 region as [N][C] f32 scratch

    hipMemsetAsync(d_ws, 0, 64, stream);
    zprep_kernel<<<512, 256, 0, stream>>>(z, z_t, z_h, A);
    bk_kernel<<<4, 256, 0, stream>>>(cb, Bk);
    cbh_kernel<<<1024, 64, 0, stream>>>(cb, cb_h);
    vq_main<<<512, 256, 0, stream>>>(z_h, cb_h, A, Bk, z_t, cb, out_idx);
    out_kernel<<<512, 256, 0, stream>>>(z, cb, out_idx, out, lacc);
    loss_kernel<<<1, 1, 0, stream>>>(lacc, out_loss);
}

// Round 13
// 117.333 us; speedup vs baseline: 28.9197x; 16.9923x over previous
//
#include <hip/hip_runtime.h>

typedef __attribute__((ext_vector_type(8))) short bf16x8;
typedef __attribute__((ext_vector_type(4))) float f32x4;

#define C_DIM 256
#define K_CODES 1024
#define HW 1024
#define N_TOK 32768
#define OUT0_ELEMS 8388608
#define NSLOT 64
#define MARGIN_P (16777u * 1024u)   // 2e-3 * 2^23, in packed units

static __device__ __forceinline__ unsigned short f2bf(float f) {
    unsigned u = __float_as_uint(f);
    unsigned r = (u + 0x7FFFu + ((u >> 16) & 1u)) >> 16;
    return (unsigned short)r;
}
static __device__ __forceinline__ unsigned umin2(unsigned a, unsigned b) { return a < b ? a : b; }

// ---------------------------------------------------------------------------
// Bk: per-code |w|^2, numpy-pairwise f32 (unchanged from passing kernel).
// ---------------------------------------------------------------------------
__global__ void bk_kernel(const float* __restrict__ cb, float* __restrict__ Bk) {
#pragma clang fp contract(off)
    int k = blockIdx.x * blockDim.x + threadIdx.x;
    if (k >= K_CODES) return;
    const float* w = cb + k * C_DIM;
    float s[2];
    for (int h = 0; h < 2; ++h) {
        const float* p = w + h * 128;
        float r[8];
        #pragma unroll
        for (int j = 0; j < 8; ++j) { float v = p[j]; r[j] = v * v; }
        for (int i = 8; i < 128; i += 8) {
            #pragma unroll
            for (int j = 0; j < 8; ++j) { float v = p[i + j]; r[j] = r[j] + v * v; }
        }
        s[h] = ((r[0] + r[1]) + (r[2] + r[3])) + ((r[4] + r[5]) + (r[6] + r[7]));
    }
    Bk[k] = s[0] + s[1];
}

// ---------------------------------------------------------------------------
// cb -> bf16 copy [K][C]
// ---------------------------------------------------------------------------
__global__ __launch_bounds__(64) void cbh_kernel(const float* __restrict__ cb,
                                                 unsigned short* __restrict__ cb_h) {
    int k = blockIdx.x, l = threadIdx.x;
    const float4 v = *(const float4*)&cb[k * C_DIM + l * 4];
    ushort4 o;
    o.x = f2bf(v.x); o.y = f2bf(v.y); o.z = f2bf(v.z); o.w = f2bf(v.w);
    *(ushort4*)&cb_h[k * C_DIM + l * 4] = o;
}

// ---------------------------------------------------------------------------
// z prep: NCHW f32 -> z_t f32 [N][C] (in d_out region, overwritten later by
// out_kernel), z_h bf16 [N][C], A[N] = |z|^2 numpy-pairwise.
// ---------------------------------------------------------------------------
__global__ __launch_bounds__(256) void zprep_kernel(const float* __restrict__ z,
        float* __restrict__ z_t, unsigned short* __restrict__ z_h,
        float* __restrict__ A) {
#pragma clang fp contract(off)
    __shared__ float tile[64 * 257];
    const int t = threadIdx.x, blk = blockIdx.x;
    const int b = blk >> 4, hw0 = (blk & 15) * 64, tok0 = blk * 64;
    const size_t zb = (size_t)b * (C_DIM * HW) + hw0;
    for (int i = 0; i < 64; ++i) {
        int pos = i * 256 + t;
        int c = pos >> 6, hw = pos & 63;
        tile[hw * 257 + c] = z[zb + (size_t)c * HW + hw];
    }
    __syncthreads();
    if (t < 64) {
        const float* p0 = &tile[t * 257];
        float s[2];
        for (int h = 0; h < 2; ++h) {
            const float* p = p0 + h * 128;
            float r[8];
            #pragma unroll
            for (int j = 0; j < 8; ++j) { float v = p[j]; r[j] = v * v; }
            for (int i = 8; i < 128; i += 8) {
                #pragma unroll
                for (int j = 0; j < 8; ++j) { float v = p[i + j]; r[j] = r[j] + v * v; }
            }
            s[h] = ((r[0] + r[1]) + (r[2] + r[3])) + ((r[4] + r[5]) + (r[6] + r[7]));
        }
        A[tok0 + t] = s[0] + s[1];
    }
    for (int i = 0; i < 64; ++i) {
        int pos = i * 256 + t;
        int tl = pos >> 8, c = pos & 255;
        float v = tile[tl * 257 + c];
        z_t[(size_t)(tok0 + tl) * 256 + c] = v;
        z_h[(size_t)(tok0 + tl) * 256 + c] = f2bf(v);
    }
}

// ---------------------------------------------------------------------------
// Main: R6's proven skeleton (afr hoist + staged wsm + same MFMA block),
// single sweep. Per (lane,slot) top-2 of PACKED (est,k) u32 replaces R6's
// bmin/mv (same register budget). Epilogue: umin-reduce -> packed threshold,
// register collect (column push on slot-overflow), exact f32 rescore.
// ---------------------------------------------------------------------------
__global__ __launch_bounds__(256, 2) void vq_main(
        const unsigned short* __restrict__ z_h, const unsigned short* __restrict__ cb_h,
        const float* __restrict__ A, const float* __restrict__ Bk,
        const float* __restrict__ z_t, const float* __restrict__ cb,
        float* __restrict__ out_idx) {
#pragma clang fp contract(off)
    __shared__ __align__(16) char zs[32768];
    __shared__ __align__(16) char wsm[32768];
    __shared__ unsigned gpart[64][4];
    __shared__ int cnt[64];
    __shared__ unsigned short ck[64 * NSLOT];
    __shared__ float bval[64][4];
    __shared__ int   bidx[64][4];

    const int tid = threadIdx.x;
    const int w = tid >> 6, l = tid & 63;
    const int lq = l >> 4, lr = l & 15;
    const int tok0 = blockIdx.x * 64;

    // stage z tile (64 tok x 256 c bf16), layout [c8][tok] 16B units, XOR-swz
    for (int i = 0; i < 8; ++i) {
        int unit = i * 256 + tid;
        int tok = unit >> 5, c8 = unit & 31;
        uint4 v = *(const uint4*)(z_h + (size_t)(tok0 + tok) * 256 + c8 * 8);
        *(uint4*)(zs + c8 * 1024 + ((tok * 16) ^ ((c8 & 7) << 4))) = v;
    }
    if (tid < 64) cnt[tid] = 0;
    __syncthreads();

    // hoist A-fragments: afr[rt][cs]; lane holds z[rt*16+lr][cs*32+lq*8 ..+8]
    bf16x8 afr[4][8];
    #pragma unroll
    for (int rt = 0; rt < 4; ++rt)
        #pragma unroll
        for (int cs = 0; cs < 8; ++cs) {
            int tok = rt * 16 + lr;
            int c8 = cs * 4 + lq;
            afr[rt][cs] = *(const bf16x8*)(zs + c8 * 1024 + ((tok * 16) ^ ((c8 & 7) << 4)));
        }

    unsigned m1p[16], m2p[16];
    #pragma unroll
    for (int s = 0; s < 16; ++s) { m1p[s] = 0xFFFFFFFFu; m2p[s] = 0xFFFFFFFFu; }

    for (int kc = 0; kc < 16; ++kc) {
        __syncthreads();
        // stage 64-code chunk of bf16 codebook, same layout/swizzle
        for (int i = 0; i < 8; ++i) {
            int unit = i * 256 + tid;
            int code = unit >> 5, c8 = unit & 31;
            uint4 v = *(const uint4*)(cb_h + (size_t)(kc * 64 + code) * 256 + c8 * 8);
            *(uint4*)(wsm + c8 * 1024 + ((code * 16) ^ ((c8 & 7) << 4))) = v;
        }
        __syncthreads();
        const int kcode = kc * 64 + w * 16 + lr;   // this lane's code column
        const float bkv = Bk[kcode];
        f32x4 acc[4];
        #pragma unroll
        for (int rt = 0; rt < 4; ++rt) acc[rt] = (f32x4){0.f, 0.f, 0.f, 0.f};
        #pragma unroll
        for (int cs = 0; cs < 8; ++cs) {
            int c8 = cs * 4 + lq;
            int codeb = w * 16 + lr;
            bf16x8 bfr = *(const bf16x8*)(wsm + c8 * 1024 + ((codeb * 16) ^ ((c8 & 7) << 4)));
            #pragma unroll
            for (int rt = 0; rt < 4; ++rt)
                acc[rt] = __builtin_amdgcn_mfma_f32_16x16x32_bf16(afr[rt][cs], bfr, acc[rt], 0, 0, 0);
        }
        // packed top-2 update (est in Bk-2dot domain; |z|^2 cancels)
        #pragma unroll
        for (int s = 0; s < 16; ++s) {
            float est = fmaf(-2.0f, acc[s >> 2][s & 3], bkv);
            float x = fmaxf(est + 0.125f, 0.0f);
            unsigned q = (unsigned)(x * 8388608.0f);
            q = umin2(q, 2097151u);
            unsigned p = q * 1024u + (unsigned)kcode;
            if (p < m1p[s])      { m2p[s] = m1p[s]; m1p[s] = p; }
            else if (p < m2p[s]) { m2p[s] = p; }
        }
    }

    // per-token min of m1p over the 16 lr-lanes, then cross-wave via gpart
    #pragma unroll
    for (int s = 0; s < 16; ++s) {
        unsigned v = m1p[s];
        v = umin2(v, (unsigned)__shfl_xor((int)v, 1));
        v = umin2(v, (unsigned)__shfl_xor((int)v, 2));
        v = umin2(v, (unsigned)__shfl_xor((int)v, 4));
        v = umin2(v, (unsigned)__shfl_xor((int)v, 8));
        if (lr == 0) gpart[(s >> 2) * 16 + lq * 4 + (s & 3)][w] = v;
    }
    __syncthreads();

    // collect candidates from registers under the packed threshold
    {
        const int colid = w * 16 + lr;
        #pragma unroll
        for (int s = 0; s < 16; ++s) {
            int tl = (s >> 2) * 16 + lq * 4 + (s & 3);
            unsigned thrp = umin2(umin2(gpart[tl][0], gpart[tl][1]),
                                  umin2(gpart[tl][2], gpart[tl][3])) + MARGIN_P;
            if (m2p[s] <= thrp) {
                // >=2 band codes in this lane-slot: push the whole 16-code column
                int pos = atomicAdd(&cnt[tl], 16);
                #pragma unroll
                for (int kc = 0; kc < 16; ++kc)
                    if (pos + kc < NSLOT) ck[tl * NSLOT + pos + kc] = (unsigned short)(kc * 64 + colid);
            } else if (m1p[s] <= thrp) {
                int pos = atomicAdd(&cnt[tl], 1);
                if (pos < NSLOT) ck[tl * NSLOT + pos] = (unsigned short)(m1p[s] & 1023u);
            }
        }
    }
    __syncthreads();

    // exact rescore (bit-identical arithmetic), 4 threads per token
    {
        int tl = tid >> 2, ln = tid & 3;
        int total = cnt[tl];
        const float* zr = z_t + (size_t)(tok0 + tl) * 256;
        float Ag = A[tok0 + tl];
        float bd = 3.4e38f; int bki = 0x7fffffff;
        if (total <= NSLOT) {
            for (int s = ln; s < total; s += 4) {
                int k = ck[tl * NSLOT + s];
                const float* wr = cb + (size_t)k * 256;
                float acc = 0.0f;
                for (int c = 0; c < 256; c += 4) {
                    float4 zv = *(const float4*)&zr[c];
                    float4 wv = *(const float4*)&wr[c];
                    acc = fmaf(zv.x, wv.x, acc);
                    acc = fmaf(zv.y, wv.y, acc);
                    acc = fmaf(zv.z, wv.z, acc);
                    acc = fmaf(zv.w, wv.w, acc);
                }
                float d = fmaf(-2.0f, acc, Ag + Bk[k]);
                if (d < bd || (d == bd && k < bki)) { bd = d; bki = k; }
            }
        } else {
            // sound fallback (P ~ 1e-9): 4-way-split exact scan of all codes
            for (int k = ln; k < K_CODES; k += 4) {
                const float* wr = cb + (size_t)k * 256;
                float acc = 0.0f;
                for (int c = 0; c < 256; c += 4) {
                    float4 zv = *(const float4*)&zr[c];
                    float4 wv = *(const float4*)&wr[c];
                    acc = fmaf(zv.x, wv.x, acc);
                    acc = fmaf(zv.y, wv.y, acc);
                    acc = fmaf(zv.z, wv.z, acc);
                    acc = fmaf(zv.w, wv.w, acc);
                }
                float d = fmaf(-2.0f, acc, Ag + Bk[k]);
                if (d < bd || (d == bd && k < bki)) { bd = d; bki = k; }
            }
        }
        bval[tl][ln] = bd; bidx[tl][ln] = bki;
    }
    __syncthreads();
    if (tid < 64) {
        float bd = bval[tid][0]; int bki = bidx[tid][0];
        #pragma unroll
        for (int j = 1; j < 4; ++j) {
            float d = bval[tid][j]; int k = bidx[tid][j];
            if (d < bd || (d == bd && k < bki)) { bd = d; bki = k; }
        }
        out_idx[tok0 + tid] = (float)bki;
    }
}

// ---------------------------------------------------------------------------
// Output: out0 = z + (w - z) elementwise (NCHW), loss partials.
// ---------------------------------------------------------------------------
__global__ __launch_bounds__(256, 2) void out_kernel(const float* __restrict__ z,
        const float* __restrict__ cb, const float* __restrict__ out_idx_f,
        float* __restrict__ out0, double* __restrict__ lacc) {
#pragma clang fp contract(off)
    __shared__ float wl[64 * 257];
    __shared__ int fi[64];
    __shared__ double red[256];
    const int t = threadIdx.x, blk = blockIdx.x;
    const int b = blk >> 4, hw0 = (blk & 15) * 64;
    const size_t zb = (size_t)b * (C_DIM * HW) + hw0;
    if (t < 64) fi[t] = (int)out_idx_f[blk * 64 + t];
    __syncthreads();
    for (int i = 0; i < 64; ++i) {
        int pos = i * 256 + t;
        int row = pos >> 8, c = pos & 255;
        wl[row * 257 + c] = cb[(size_t)fi[row] * 256 + c];
    }
    __syncthreads();
    double lsum = 0.0;
    for (int i = 0; i < 64; ++i) {
        int pos = i * 256 + t;
        int c = pos >> 6, hw = pos & 63;
        float zv = z[zb + (size_t)c * HW + hw];
        float wv = wl[hw * 257 + c];
        float d = wv - zv;
        out0[zb + (size_t)c * HW + hw] = zv + d;
        float q = d * d;
        lsum += (double)q;
    }
    red[t] = lsum;
    __syncthreads();
    if (t == 0) {
        double s = 0.0;
        for (int i = 0; i < 256; ++i) s += red[i];
        atomicAdd(lacc, s);
    }
}

__global__ void loss_kernel(const double* __restrict__ acc, float* __restrict__ out_loss) {
    double mse = acc[0] / (double)OUT0_ELEMS;
    out_loss[0] = (float)(mse + 0.25 * mse);
}

extern "C" void kernel_launch(void* const* d_in, const int* in_sizes, int n_in,
                              void* d_out, int out_size, void* d_ws, size_t ws_size,
                              hipStream_t stream) {
    const float* z  = (const float*)d_in[0];
    const float* cb = (const float*)d_in[1];
    float* out      = (float*)d_out;
    float* out_idx  = out + OUT0_ELEMS;
    float* out_loss = out + OUT0_ELEMS + N_TOK;

    char* wsb = (char*)d_ws;
    double*         lacc = (double*)wsb;                       // 64 B
    float*          Bk   = (float*)(wsb + 64);                 // 4 KB
    float*          A    = (float*)(wsb + 8192);               // 128 KB
    unsigned short* cb_h = (unsigned short*)(wsb + 262144);    // 512 KB
    unsigned short* z_h  = (unsigned short*)(wsb + 1048576);   // 16 MB
    float*          z_t  = out;  // reuse out0 region as [N][C] f32 scratch

    hipMemsetAsync(d_ws, 0, 64, stream);
    zprep_kernel<<<512, 256, 0, stream>>>(z, z_t, z_h, A);
    bk_kernel<<<4, 256, 0, stream>>>(cb, Bk);
    cbh_kernel<<<1024, 64, 0, stream>>>(cb, cb_h);
    vq_main<<<512, 256, 0, stream>>>(z_h, cb_h, A, Bk, z_t, cb, out_idx);
    out_kernel<<<512, 256, 0, stream>>>(z, cb, out_idx, out, lacc);
    loss_kernel<<<1, 1, 0, stream>>>(lacc, out_loss);
}